// Round 7
// baseline (1617.151 us; speedup 1.0000x reference)
//
#include <hip/hip_runtime.h>

#define TPB 512
#define BM 128
#define AS 128   // activation row stride in floats

// ===========================================================================
// CSR build: count -> block scan -> fixup -> scatter. Rebuilt every call.
// ===========================================================================
__global__ void count_kernel(const int* __restrict__ ei, int* __restrict__ cnt, int E)
{
    int e = blockIdx.x * blockDim.x + threadIdx.x;
    if (e >= E) return;
    atomicAdd(cnt + ei[E + e], 1);
}

__global__ void scan_blocks(const int* __restrict__ cnt, int* __restrict__ rs,
                            int* __restrict__ part, int N)
{
    __shared__ int sums[256];
    int t = threadIdx.x;
    int base = blockIdx.x * 2048 + t * 8;
    int v[8], s = 0;
#pragma unroll
    for (int i = 0; i < 8; i++) { int idx = base + i; v[i] = (idx < N) ? cnt[idx] : 0; s += v[i]; }
    sums[t] = s;
    __syncthreads();
    for (int off = 1; off < 256; off <<= 1) {
        int x = (t >= off) ? sums[t - off] : 0;
        __syncthreads();
        if (t >= off) sums[t] += x;
        __syncthreads();
    }
    int run = (t == 0) ? 0 : sums[t - 1];
#pragma unroll
    for (int i = 0; i < 8; i++) { int idx = base + i; if (idx < N) rs[idx] = run; run += v[i]; }
    if (t == 255) part[blockIdx.x] = sums[255];
}

__global__ void scan_part(int* __restrict__ part, int nb)
{
    __shared__ int sums[256];
    int t = threadIdx.x;
    int base = t * 8;
    int v[8], s = 0;
#pragma unroll
    for (int i = 0; i < 8; i++) { int idx = base + i; v[i] = (idx < nb) ? part[idx] : 0; s += v[i]; }
    sums[t] = s;
    __syncthreads();
    for (int off = 1; off < 256; off <<= 1) {
        int x = (t >= off) ? sums[t - off] : 0;
        __syncthreads();
        if (t >= off) sums[t] += x;
        __syncthreads();
    }
    int run = (t == 0) ? 0 : sums[t - 1];
#pragma unroll
    for (int i = 0; i < 8; i++) { int idx = base + i; if (idx < nb) part[idx] = run; run += v[i]; }
}

__global__ void scan_fixup(int* __restrict__ rs, int* __restrict__ cursor,
                           const int* __restrict__ part, int N, int E)
{
    int i = blockIdx.x * blockDim.x + threadIdx.x;
    if (i < N) { int v = rs[i] + part[i >> 11]; rs[i] = v; cursor[i] = v; }
    if (i == 0) rs[N] = E;
}

__global__ void scatter_kernel(const int* __restrict__ ei, int* __restrict__ cursor,
                               int* __restrict__ col, int E)
{
    int e = blockIdx.x * blockDim.x + threadIdx.x;
    if (e >= E) return;
    int d = ei[E + e];
    int p = atomicAdd(cursor + d, 1);
    col[p] = ei[e];
}

// ===========================================================================
// Async DMA global->LDS, 16B per lane. LDS dest = wave-uniform base + lane*16
// (hardware adds the lane offset); global src is per-lane. Zero VGPRs held ->
// cannot spill (rounds 4/5 showed register prefetch spills in this kernel).
// ===========================================================================
__device__ __forceinline__ void async_copy16(const float* g, float* l)
{
    __builtin_amdgcn_global_load_lds(
        (const __attribute__((address_space(1))) unsigned int*)g,
        (__attribute__((address_space(3))) unsigned int*)l,
        16, 0, 0);
}

// ===========================================================================
// FMA over one 4KB weight chunk in LDS. 128-row tile, 8 rows/thread in two
// 4-row halves. All acc indices compile-time.
// ===========================================================================
template<int CPT>
__device__ __forceinline__ void chunk_fma(const float* __restrict__ act,
                                          const float* __restrict__ wc,
                                          int kb, int rows, int r0, int c0,
                                          float (&acc)[8][CPT])
{
    constexpr int C = CPT * 32;
    for (int k = 0; k < rows; k += 4) {
#pragma unroll
        for (int h = 0; h < 2; h++) {
            const int rr = r0 + h * 4;
            float4 a0 = *(const float4*)(act + (rr + 0) * AS + kb + k);
            float4 a1 = *(const float4*)(act + (rr + 1) * AS + kb + k);
            float4 a2 = *(const float4*)(act + (rr + 2) * AS + kb + k);
            float4 a3 = *(const float4*)(act + (rr + 3) * AS + kb + k);
#pragma unroll
            for (int kk = 0; kk < 4; kk++) {
                float b[CPT];
                if (CPT == 4) {
                    float4 bv = *(const float4*)(wc + (k + kk) * C + c0);
                    b[0] = bv.x; b[1] = bv.y; b[2] = bv.z; b[3] = bv.w;
                } else {
                    float2 bv = *(const float2*)(wc + (k + kk) * C + c0);
                    b[0] = bv.x; b[1] = bv.y;
                }
                float av[4];
                av[0] = ((const float*)&a0)[kk];
                av[1] = ((const float*)&a1)[kk];
                av[2] = ((const float*)&a2)[kk];
                av[3] = ((const float*)&a3)[kk];
#pragma unroll
                for (int i = 0; i < 4; i++)
#pragma unroll
                    for (int j = 0; j < CPT; j++)
                        acc[h * 4 + i][j] = fmaf(av[i], b[j], acc[h * 4 + i][j]);
            }
        }
    }
}

// ===========================================================================
// In-place GEMM layer, double-buffered 4KB weight chunks staged via async
// global_load_lds issued BEFORE the current chunk's FMA body; __syncthreads'
// implicit vmcnt(0) drain publishes it (m97 pattern). One barrier per chunk,
// load latency hidden under ~512 cyc of FMA. Bounds-checked reg-stage only
// for partial tail chunks (uW1's 67->68 pad).
//   act[r][0:C] = f(sum_k act[r][k]*W[k][c] + scale(r)*bias[c])
// ===========================================================================
template<int CPT>
__device__ __forceinline__ void gemm_layer(
    float* __restrict__ act, const float* __restrict__ Wg,
    const float* __restrict__ bias_g, const float* __restrict__ ldeg,
    float* __restrict__ wbuf,                 // 2*1024 floats (two 4KB halves)
    int K_real, int K_pad, bool relu,
    float* __restrict__ state_g, long base, int n)
{
    constexpr int C = CPT * 32;
    constexpr int RPC = 1024 / C;             // rows per 4KB chunk (16 or 8)
    const int tid = threadIdx.x;
    const int tx = tid & 31;
    const int ty = tid >> 5;
    const int r0 = ty * 8;
    const int c0 = tx * CPT;
    const int nc = (K_pad + RPC - 1) / RPC;
    const int wave = tid >> 6;
    const int lane = tid & 63;

    // async full-chunk stage: chunk c is floats [c*1024, c*1024+1024) of Wg
    // (row-major, so a chunk is contiguous). 4 waves x 64 lanes x 16B = 4KB.
    auto stage_async = [&](int c, float* dst) {
        if (wave < 4)
            async_copy16(Wg + (long)c * 1024 + wave * 256 + lane * 4,
                         dst + wave * 256);
    };
    // bounds-checked fallback for chunks touching rows >= K_real
    auto stage_tail = [&](int c, float* dst) {
        int kb = c * RPC;
        int rows = K_pad - kb; if (rows > RPC) rows = RPC;
        for (int i = tid; i < rows * C; i += TPB) {
            int gk = kb + i / C;
            dst[i] = (gk < K_real) ? Wg[(long)kb * C + i] : 0.0f;
        }
    };

    float acc[8][CPT];
#pragma unroll
    for (int i = 0; i < 8; i++)
#pragma unroll
        for (int j = 0; j < CPT; j++) acc[i][j] = 0.0f;

    // prologue: chunk 0
    if (RPC <= K_real) stage_async(0, wbuf);
    else               stage_tail(0, wbuf);
    __syncthreads();   // drains vmcnt -> chunk 0 resident

    for (int c = 0; c < nc; ++c) {
        float* cur = wbuf + (c & 1) * 1024;
        float* nxt = wbuf + ((c + 1) & 1) * 1024;
        // issue next chunk's DMA now; it completes during this chunk's FMAs.
        // nxt's last readers finished at the barrier ending chunk c-1.
        if (c + 1 < nc) {
            if ((c + 2) * RPC <= K_real) stage_async(c + 1, nxt);
            else                         stage_tail(c + 1, nxt);
        }
        const int kb = c * RPC;
        int rows = K_pad - kb; if (rows > RPC) rows = RPC;
        chunk_fma<CPT>(act, cur, kb, rows, r0, c0, acc);
        __syncthreads();   // all reads of cur done; nxt published (vmcnt drain)
    }

    // all act reads done (barrier above) -> write outputs in place
#pragma unroll
    for (int i = 0; i < 8; i++) {
        int r = r0 + i;
        float scale = ldeg ? ldeg[r] : 1.0f;
        float vv[CPT];
#pragma unroll
        for (int j = 0; j < CPT; j++) {
            float v = acc[i][j] + scale * bias_g[c0 + j];
            if (relu) v = fmaxf(v, 0.0f);
            vv[j] = v;
        }
        if (CPT == 4) *(float4*)(act + r * AS + c0) = make_float4(vv[0], vv[1], vv[2], vv[3]);
        else          *(float2*)(act + r * AS + c0) = make_float2(vv[0], vv[1]);
        if (state_g != nullptr && base + r < n) {
            if (CPT == 4) *(float4*)(state_g + (base + r) * 64 + c0) = make_float4(vv[0], vv[1], vv[2], vv[3]);
            else          *(float2*)(state_g + (base + r) * 64 + c0) = make_float2(vv[0], vv[1]);
        }
    }
    __syncthreads();
}

// ===========================================================================
// Fused per-128-node-tile: CSR gather -> layer0 -> update MLP -> predictor.
// LDS = 64KB act + 8KB wbuf + 0.5KB ldeg = 72.5KB -> 2 blocks/CU.
// ===========================================================================
template<int K0>
__global__ __launch_bounds__(TPB, 4)
void fused_kernel(const int* __restrict__ rs, const int* __restrict__ col,
                  const float* __restrict__ srcdat, int nvar,
                  const float* __restrict__ xg,
                  const float* __restrict__ W0, const float* __restrict__ b0,
                  const float* __restrict__ uW1, const float* __restrict__ ub1,
                  const float* __restrict__ uW2, const float* __restrict__ ub2,
                  const float* __restrict__ uW3, const float* __restrict__ ub3,
                  const float* __restrict__ pW1, const float* __restrict__ pb1,
                  const float* __restrict__ pW2, const float* __restrict__ pb2,
                  const float* __restrict__ pW3, const float* __restrict__ pb3,
                  float* __restrict__ state_g, float* __restrict__ outg, int n)
{
    __shared__ float act[BM * AS];
    __shared__ float wbuf[2 * 1024];
    __shared__ float ldeg[BM];

    const int tid = threadIdx.x;
    const long base = (long)blockIdx.x * BM;
    const int nvar2 = 2 * nvar;
    const int wave = tid >> 6;
    const int lane = tid & 63;

    // ---- CSR gather into act[:, 0:K0]; deg -> ldeg
    if constexpr (K0 == 64) {
        for (int i = 0; i < 16; i++) {
            int node = wave * 16 + i;
            long g = base + node;
            int d0 = 0, d1 = 0;
            if (g < n) { d0 = rs[g]; d1 = rs[g + 1]; }
            float acc = 0.0f;
            int e = d0;
            for (; e + 4 <= d1; e += 4) {
                int s0 = col[e], s1 = col[e + 1], s2 = col[e + 2], s3 = col[e + 3];
                float a0 = (s0 < nvar2) ? srcdat[(long)s0 * 64 + lane] : 0.0f;
                float a1 = (s1 < nvar2) ? srcdat[(long)s1 * 64 + lane] : 0.0f;
                float a2 = (s2 < nvar2) ? srcdat[(long)s2 * 64 + lane] : 0.0f;
                float a3 = (s3 < nvar2) ? srcdat[(long)s3 * 64 + lane] : 0.0f;
                acc += a0 + a1 + a2 + a3;
            }
            for (; e < d1; e++) {
                int s = col[e];
                if (s < nvar2) acc += srcdat[(long)s * 64 + lane];
            }
            act[node * AS + lane] = acc;
            if (lane == 0) ldeg[node] = (float)(d1 - d0);
        }
    } else {
        const int f = lane & 15, sub = lane >> 4;
        for (int i = 0; i < 4; i++) {
            int node = wave * 16 + i * 4 + sub;
            long g = base + node;
            int d0 = 0, d1 = 0;
            if (g < n) { d0 = rs[g]; d1 = rs[g + 1]; }
            float acc = 0.0f;
            int e = d0;
            for (; e + 2 <= d1; e += 2) {
                int s0 = col[e], s1 = col[e + 1];
                float a0 = 0.0f, a1 = 0.0f;
                if (s0 < nvar2) {
                    a0 = srcdat[(long)((s0 < nvar) ? s0 : s0 - nvar) * 16 + f];
                    if (s0 >= nvar) a0 = -a0;
                }
                if (s1 < nvar2) {
                    a1 = srcdat[(long)((s1 < nvar) ? s1 : s1 - nvar) * 16 + f];
                    if (s1 >= nvar) a1 = -a1;
                }
                acc += a0 + a1;
            }
            for (; e < d1; e++) {
                int s = col[e];
                if (s < nvar2) {
                    float a = srcdat[(long)((s < nvar) ? s : s - nvar) * 16 + f];
                    acc += (s < nvar) ? a : -a;
                }
            }
            act[node * AS + f] = acc;
            if (f == 0) ldeg[node] = (float)(d1 - d0);
        }
    }
    __syncthreads();

    // ---- layer0: msg = gather@W0 + deg*b0 (reads cols 0:K0, writes 0:64)
    gemm_layer<2>(act, W0, b0, ldeg, wbuf, K0, K0, false, nullptr, base, n);

    // stage x -> cols 64..66, zero col 67 (ordered by next layer's stage-sync)
    for (int idx = tid; idx < BM * 3; idx += TPB) {
        int node = idx / 3, j = idx % 3;
        float v = (base + node < n) ? xg[(base + node) * 3 + j] : 0.0f;
        act[node * AS + 64 + j] = v;
    }
    for (int idx = tid; idx < BM; idx += TPB) act[idx * AS + 67] = 0.0f;

    // ---- update MLP
    gemm_layer<4>(act, uW1, ub1, nullptr, wbuf, 67, 68, true, nullptr, base, n);
    gemm_layer<4>(act, uW2, ub2, nullptr, wbuf, 128, 128, true, nullptr, base, n);
    gemm_layer<2>(act, uW3, ub3, nullptr, wbuf, 128, 128, false, state_g, base, n);

    // ---- predictor MLP
    gemm_layer<4>(act, pW1, pb1, nullptr, wbuf, 64, 64, true, nullptr, base, n);
    gemm_layer<4>(act, pW2, pb2, nullptr, wbuf, 128, 128, true, nullptr, base, n);

    // ---- predictor layer3: 128 -> 2
    for (int i = tid; i < 64; i += TPB)
        ((float4*)wbuf)[i] = ((const float4*)pW3)[i];
    __syncthreads();
    if (tid < 256) {
        int r = tid >> 1, c = tid & 1;
        float acc = pb3[c];
        for (int k = 0; k < 128; k += 4) {
            float4 a = *(const float4*)(act + r * AS + k);
            acc = fmaf(a.x, wbuf[(k + 0) * 2 + c], acc);
            acc = fmaf(a.y, wbuf[(k + 1) * 2 + c], acc);
            acc = fmaf(a.z, wbuf[(k + 2) * 2 + c], acc);
            acc = fmaf(a.w, wbuf[(k + 3) * 2 + c], acc);
        }
        if (base + r < n) outg[(base + r) * 2 + c] = acc;
    }
}

// ===========================================================================
extern "C" void kernel_launch(void* const* d_in, const int* in_sizes, int n_in,
                              void* d_out, int out_size, void* d_ws, size_t ws_size,
                              hipStream_t stream)
{
    const float* x    = (const float*)d_in[0];
    const int*   ei   = (const int*)d_in[1];
    // d_in[2] = gate_type: fixed ordering [VAR*nvar, NEGVAR*nvar, CLAUSE*ncla]
    const float* posr = (const float*)d_in[3];
    const float* Wr   = (const float*)d_in[4];
    const float* br   = (const float*)d_in[5];
    const float* Wc   = (const float*)d_in[6];
    const float* bc   = (const float*)d_in[7];
    const float* uW1  = (const float*)d_in[8];
    const float* ub1  = (const float*)d_in[9];
    const float* uW2  = (const float*)d_in[10];
    const float* ub2  = (const float*)d_in[11];
    const float* uW3  = (const float*)d_in[12];
    const float* ub3  = (const float*)d_in[13];
    const float* pW1  = (const float*)d_in[14];
    const float* pb1  = (const float*)d_in[15];
    const float* pW2  = (const float*)d_in[16];
    const float* pb2  = (const float*)d_in[17];
    const float* pW3  = (const float*)d_in[18];
    const float* pb3  = (const float*)d_in[19];

    const int N     = in_sizes[0] / 3;
    const int E     = in_sizes[1] / 2;
    const int nvar  = in_sizes[3] / 16;
    const int nvar2 = 2 * nvar;
    const int ncla  = N - nvar2;

    // workspace carve-out
    int* cnt    = (int*)d_ws;              // [N]
    int* rs     = cnt + N;                 // [N+1]
    int* cursor = rs + N + 1;              // [N]
    int* part   = cursor + N;              // [2048]
    int* col    = part + 2048;             // [E]
    size_t foff = ((size_t)(col + E - (int*)d_ws) + 3) & ~(size_t)3;
    float* state = (float*)d_ws + foff;    // [2nvar*64]

    hipMemsetAsync(cnt, 0, (size_t)N * sizeof(int), stream);

    const int nb = (N + 2047) / 2048;
    count_kernel<<<(E + 255) / 256, 256, 0, stream>>>(ei, cnt, E);
    scan_blocks<<<nb, 256, 0, stream>>>(cnt, rs, part, N);
    scan_part<<<1, 256, 0, stream>>>(part, nb);
    scan_fixup<<<(N + 255) / 256, 256, 0, stream>>>(rs, cursor, part, N, E);
    scatter_kernel<<<(E + 255) / 256, 256, 0, stream>>>(ei, cursor, col, E);

    {   // var + negvar partitions (gather pos_random via CSR)
        int blocks = (nvar2 + BM - 1) / BM;
        fused_kernel<16><<<blocks, TPB, 0, stream>>>(
            rs, col, posr, nvar, x, Wr, br,
            uW1, ub1, uW2, ub2, uW3, ub3,
            pW1, pb1, pW2, pb2, pW3, pb3,
            state, (float*)d_out, nvar2);
    }

    {   // clause partition (gather state via CSR, rows offset by 2nvar)
        int blocks = (ncla + BM - 1) / BM;
        fused_kernel<64><<<blocks, TPB, 0, stream>>>(
            rs + nvar2, col, state, nvar, x + (size_t)nvar2 * 3, Wc, bc,
            uW1, ub1, uW2, ub2, uW3, ub3,
            pW1, pb1, pW2, pb2, pW3, pb3,
            nullptr, (float*)d_out + (size_t)nvar2 * 2, ncla);
    }
}

// Round 8
// 1551.438 us; speedup vs baseline: 1.0424x; 1.0424x over previous
//
#include <hip/hip_runtime.h>

#define TPB 512
#define BM 128
#define AS 128   // activation row stride in floats (swizzled, no pad needed)

// ===========================================================================
// CSR build: count -> block scan -> fixup -> scatter. Rebuilt every call.
// ===========================================================================
__global__ void count_kernel(const int* __restrict__ ei, int* __restrict__ cnt, int E)
{
    int e = blockIdx.x * blockDim.x + threadIdx.x;
    if (e >= E) return;
    atomicAdd(cnt + ei[E + e], 1);
}

__global__ void scan_blocks(const int* __restrict__ cnt, int* __restrict__ rs,
                            int* __restrict__ part, int N)
{
    __shared__ int sums[256];
    int t = threadIdx.x;
    int base = blockIdx.x * 2048 + t * 8;
    int v[8], s = 0;
#pragma unroll
    for (int i = 0; i < 8; i++) { int idx = base + i; v[i] = (idx < N) ? cnt[idx] : 0; s += v[i]; }
    sums[t] = s;
    __syncthreads();
    for (int off = 1; off < 256; off <<= 1) {
        int x = (t >= off) ? sums[t - off] : 0;
        __syncthreads();
        if (t >= off) sums[t] += x;
        __syncthreads();
    }
    int run = (t == 0) ? 0 : sums[t - 1];
#pragma unroll
    for (int i = 0; i < 8; i++) { int idx = base + i; if (idx < N) rs[idx] = run; run += v[i]; }
    if (t == 255) part[blockIdx.x] = sums[255];
}

__global__ void scan_part(int* __restrict__ part, int nb)
{
    __shared__ int sums[256];
    int t = threadIdx.x;
    int base = t * 8;
    int v[8], s = 0;
#pragma unroll
    for (int i = 0; i < 8; i++) { int idx = base + i; v[i] = (idx < nb) ? part[idx] : 0; s += v[i]; }
    sums[t] = s;
    __syncthreads();
    for (int off = 1; off < 256; off <<= 1) {
        int x = (t >= off) ? sums[t - off] : 0;
        __syncthreads();
        if (t >= off) sums[t] += x;
        __syncthreads();
    }
    int run = (t == 0) ? 0 : sums[t - 1];
#pragma unroll
    for (int i = 0; i < 8; i++) { int idx = base + i; if (idx < nb) part[idx] = run; run += v[i]; }
}

__global__ void scan_fixup(int* __restrict__ rs, int* __restrict__ cursor,
                           const int* __restrict__ part, int N, int E)
{
    int i = blockIdx.x * blockDim.x + threadIdx.x;
    if (i < N) { int v = rs[i] + part[i >> 11]; rs[i] = v; cursor[i] = v; }
    if (i == 0) rs[N] = E;
}

__global__ void scatter_kernel(const int* __restrict__ ei, int* __restrict__ cursor,
                               int* __restrict__ col, int E)
{
    int e = blockIdx.x * blockDim.x + threadIdx.x;
    if (e >= E) return;
    int d = ei[E + e];
    int p = atomicAdd(cursor + d, 1);
    col[p] = ei[e];
}

// ===========================================================================
// act LDS swizzle: float4-slot XOR'd with (row&7). Row-stride accesses
// (lane = row, fixed col) would otherwise be 64-way same-bank; swizzle
// spreads the 8 bank-groups -> conflict-free. Bijective per row.
// ===========================================================================
__device__ __forceinline__ int swz(int r, int col)
{
    return r * AS + ((((col >> 2) ^ (r & 7)) << 2) | (col & 3));
}

// ===========================================================================
// Scalar-weight GEMM layer: wave = 64 rows (lane=row) x CW=C/4 columns.
// Weight element W[k][c] is wave-uniform -> s_load through K$ (scalar pipe),
// consumed as the single legal SGPR operand of v_fma_f32. LDS traffic:
// ONE ds_read_b128 (lane's act row) per 128 FMAs. No weight staging at all.
//   act[r][0:C] = f(sum_k act[r][k]*W[k][c] + scale(r)*bias[c])  in place
// ===========================================================================
template<int C, bool RELU>
__device__ __forceinline__ void scalar_gemm(
    float* __restrict__ act,
    const float* __restrict__ Wg, const float* __restrict__ bias_g,
    const float* __restrict__ ldeg,            // non-null: scale = ldeg[r]
    int K_real, int K_pad,                     // K_pad multiple of 4; rows
    float* __restrict__ state_g, long base, int n)
{
    constexpr int CW = C / 4;                  // columns per wave (16 or 32)
    const int tid  = threadIdx.x;
    const int wid  = __builtin_amdgcn_readfirstlane(tid >> 6);  // compiler-uniform
    const int lane = tid & 63;
    const int r    = (wid & 1) * 64 + lane;    // lane = row within 64-row half
    const int c0   = (wid >> 1) * CW;          // wave-uniform column base

    float acc[CW];
#pragma unroll
    for (int j = 0; j < CW; j++) acc[j] = 0.0f;

    for (int k4 = 0; k4 < K_pad; k4 += 4) {
        float4 a = *(const float4*)(act + r * AS + (((k4 >> 2) ^ (r & 7)) << 2));
#pragma unroll
        for (int kk = 0; kk < 4; kk++) {
            int gk = k4 + kk;
            int wrow = (gk < K_real) ? gk : 0;       // clamp (act pad col = 0)
            float av = (&a.x)[kk];
            const float* wr = Wg + (long)wrow * C + c0;   // uniform -> s_load
#pragma unroll
            for (int j4 = 0; j4 < CW / 4; j4++) {
                float4 wv = *(const float4*)(wr + j4 * 4);
                acc[j4 * 4 + 0] = fmaf(av, wv.x, acc[j4 * 4 + 0]);
                acc[j4 * 4 + 1] = fmaf(av, wv.y, acc[j4 * 4 + 1]);
                acc[j4 * 4 + 2] = fmaf(av, wv.z, acc[j4 * 4 + 2]);
                acc[j4 * 4 + 3] = fmaf(av, wv.w, acc[j4 * 4 + 3]);
            }
        }
    }
    float scale = (ldeg != nullptr) ? ldeg[r] : 1.0f;
    __syncthreads();       // all waves' act reads complete
#pragma unroll
    for (int j4 = 0; j4 < CW / 4; j4++) {
        int cc = c0 + j4 * 4;
        float4 bv = *(const float4*)(bias_g + cc);        // uniform -> s_load
        float4 o;
        o.x = acc[j4 * 4 + 0] + scale * bv.x;
        o.y = acc[j4 * 4 + 1] + scale * bv.y;
        o.z = acc[j4 * 4 + 2] + scale * bv.z;
        o.w = acc[j4 * 4 + 3] + scale * bv.w;
        if (RELU) {
            o.x = fmaxf(o.x, 0.0f); o.y = fmaxf(o.y, 0.0f);
            o.z = fmaxf(o.z, 0.0f); o.w = fmaxf(o.w, 0.0f);
        }
        *(float4*)(act + r * AS + (((cc >> 2) ^ (r & 7)) << 2)) = o;
        if (state_g != nullptr && base + r < n)
            *(float4*)(state_g + (base + r) * 64 + cc) = o;
    }
    __syncthreads();       // new act visible
}

// ===========================================================================
// Fused per-128-node-tile: CSR gather -> layer0 -> update MLP -> predictor.
// LDS = 64KB swizzled act + ldeg -> 2 blocks/CU. No weight LDS.
// ===========================================================================
template<int K0>
__global__ __launch_bounds__(TPB, 4)
void fused_kernel(const int* __restrict__ rs, const int* __restrict__ col,
                  const float* __restrict__ srcdat, int nvar,
                  const float* __restrict__ xg,
                  const float* __restrict__ W0, const float* __restrict__ b0,
                  const float* __restrict__ uW1, const float* __restrict__ ub1,
                  const float* __restrict__ uW2, const float* __restrict__ ub2,
                  const float* __restrict__ uW3, const float* __restrict__ ub3,
                  const float* __restrict__ pW1, const float* __restrict__ pb1,
                  const float* __restrict__ pW2, const float* __restrict__ pb2,
                  const float* __restrict__ pW3, const float* __restrict__ pb3,
                  float* __restrict__ state_g, float* __restrict__ outg, int n)
{
    __shared__ float act[BM * AS];
    __shared__ float ldeg[BM];

    const int tid = threadIdx.x;
    const long base = (long)blockIdx.x * BM;
    const int nvar2 = 2 * nvar;
    const int wave = tid >> 6;
    const int lane = tid & 63;

    // ---- CSR gather into act[:, 0:K0] (swizzled); deg -> ldeg
    if constexpr (K0 == 64) {
        for (int i = 0; i < 16; i++) {
            int node = wave * 16 + i;
            long g = base + node;
            int d0 = 0, d1 = 0;
            if (g < n) { d0 = rs[g]; d1 = rs[g + 1]; }
            float acc = 0.0f;
            int e = d0;
            for (; e + 4 <= d1; e += 4) {
                int s0 = col[e], s1 = col[e + 1], s2 = col[e + 2], s3 = col[e + 3];
                float a0 = (s0 < nvar2) ? srcdat[(long)s0 * 64 + lane] : 0.0f;
                float a1 = (s1 < nvar2) ? srcdat[(long)s1 * 64 + lane] : 0.0f;
                float a2 = (s2 < nvar2) ? srcdat[(long)s2 * 64 + lane] : 0.0f;
                float a3 = (s3 < nvar2) ? srcdat[(long)s3 * 64 + lane] : 0.0f;
                acc += a0 + a1 + a2 + a3;
            }
            for (; e < d1; e++) {
                int s = col[e];
                if (s < nvar2) acc += srcdat[(long)s * 64 + lane];
            }
            act[swz(node, lane)] = acc;
            if (lane == 0) ldeg[node] = (float)(d1 - d0);
        }
    } else {
        const int f = lane & 15, sub = lane >> 4;
        for (int i = 0; i < 4; i++) {
            int node = wave * 16 + i * 4 + sub;
            long g = base + node;
            int d0 = 0, d1 = 0;
            if (g < n) { d0 = rs[g]; d1 = rs[g + 1]; }
            float acc = 0.0f;
            int e = d0;
            for (; e + 2 <= d1; e += 2) {
                int s0 = col[e], s1 = col[e + 1];
                float a0 = 0.0f, a1 = 0.0f;
                if (s0 < nvar2) {
                    a0 = srcdat[(long)((s0 < nvar) ? s0 : s0 - nvar) * 16 + f];
                    if (s0 >= nvar) a0 = -a0;
                }
                if (s1 < nvar2) {
                    a1 = srcdat[(long)((s1 < nvar) ? s1 : s1 - nvar) * 16 + f];
                    if (s1 >= nvar) a1 = -a1;
                }
                acc += a0 + a1;
            }
            for (; e < d1; e++) {
                int s = col[e];
                if (s < nvar2) {
                    float a = srcdat[(long)((s < nvar) ? s : s - nvar) * 16 + f];
                    acc += (s < nvar) ? a : -a;
                }
            }
            act[swz(node, f)] = acc;
            if (f == 0) ldeg[node] = (float)(d1 - d0);
        }
    }
    // ---- stage x into cols 64..66, zero col 67 (disjoint from layer0's
    // read cols 0..K0-1 and write cols 0..63 -> no extra barrier needed)
    for (int idx = tid; idx < BM * 4; idx += TPB) {
        int node = idx >> 2, j = idx & 3;
        float v = 0.0f;
        if (j < 3 && base + node < n) v = xg[(base + node) * 3 + j];
        act[swz(node, 64 + j)] = v;
    }
    __syncthreads();

    // ---- layer0: msg = gather@W0 + deg*b0 (reads 0:K0, writes 0:64)
    scalar_gemm<64, false>(act, W0, b0, ldeg, K0, K0, nullptr, base, n);
    // ---- update MLP (uW1 is 67x128; K_pad=68 with wrow clamp, act[67]=0)
    scalar_gemm<128, true >(act, uW1, ub1, nullptr, 67, 68, nullptr, base, n);
    scalar_gemm<128, true >(act, uW2, ub2, nullptr, 128, 128, nullptr, base, n);
    scalar_gemm<64, false>(act, uW3, ub3, nullptr, 128, 128, state_g, base, n);
    // ---- predictor MLP
    scalar_gemm<128, true >(act, pW1, pb1, nullptr, 64, 64, nullptr, base, n);
    scalar_gemm<128, true >(act, pW2, pb2, nullptr, 128, 128, nullptr, base, n);

    // ---- predictor layer3: 128 -> 2 (tiny; pW3 hot in cache)
    if (tid < 256) {
        int r = tid >> 1, c = tid & 1;
        float acc = pb3[c];
        for (int k = 0; k < 128; k += 4) {
            float4 a = *(const float4*)(act + r * AS + (((k >> 2) ^ (r & 7)) << 2));
            acc = fmaf(a.x, pW3[(k + 0) * 2 + c], acc);
            acc = fmaf(a.y, pW3[(k + 1) * 2 + c], acc);
            acc = fmaf(a.z, pW3[(k + 2) * 2 + c], acc);
            acc = fmaf(a.w, pW3[(k + 3) * 2 + c], acc);
        }
        if (base + r < n) outg[(base + r) * 2 + c] = acc;
    }
}

// ===========================================================================
extern "C" void kernel_launch(void* const* d_in, const int* in_sizes, int n_in,
                              void* d_out, int out_size, void* d_ws, size_t ws_size,
                              hipStream_t stream)
{
    const float* x    = (const float*)d_in[0];
    const int*   ei   = (const int*)d_in[1];
    // d_in[2] = gate_type: fixed ordering [VAR*nvar, NEGVAR*nvar, CLAUSE*ncla]
    const float* posr = (const float*)d_in[3];
    const float* Wr   = (const float*)d_in[4];
    const float* br   = (const float*)d_in[5];
    const float* Wc   = (const float*)d_in[6];
    const float* bc   = (const float*)d_in[7];
    const float* uW1  = (const float*)d_in[8];
    const float* ub1  = (const float*)d_in[9];
    const float* uW2  = (const float*)d_in[10];
    const float* ub2  = (const float*)d_in[11];
    const float* uW3  = (const float*)d_in[12];
    const float* ub3  = (const float*)d_in[13];
    const float* pW1  = (const float*)d_in[14];
    const float* pb1  = (const float*)d_in[15];
    const float* pW2  = (const float*)d_in[16];
    const float* pb2  = (const float*)d_in[17];
    const float* pW3  = (const float*)d_in[18];
    const float* pb3  = (const float*)d_in[19];

    const int N     = in_sizes[0] / 3;
    const int E     = in_sizes[1] / 2;
    const int nvar  = in_sizes[3] / 16;
    const int nvar2 = 2 * nvar;
    const int ncla  = N - nvar2;

    // workspace carve-out
    int* cnt    = (int*)d_ws;              // [N]
    int* rs     = cnt + N;                 // [N+1]
    int* cursor = rs + N + 1;              // [N]
    int* part   = cursor + N;              // [2048]
    int* col    = part + 2048;             // [E]
    size_t foff = ((size_t)(col + E - (int*)d_ws) + 3) & ~(size_t)3;
    float* state = (float*)d_ws + foff;    // [2nvar*64]

    hipMemsetAsync(cnt, 0, (size_t)N * sizeof(int), stream);

    const int nb = (N + 2047) / 2048;
    count_kernel<<<(E + 255) / 256, 256, 0, stream>>>(ei, cnt, E);
    scan_blocks<<<nb, 256, 0, stream>>>(cnt, rs, part, N);
    scan_part<<<1, 256, 0, stream>>>(part, nb);
    scan_fixup<<<(N + 255) / 256, 256, 0, stream>>>(rs, cursor, part, N, E);
    scatter_kernel<<<(E + 255) / 256, 256, 0, stream>>>(ei, cursor, col, E);

    {   // var + negvar partitions (gather pos_random via CSR)
        int blocks = (nvar2 + BM - 1) / BM;
        fused_kernel<16><<<blocks, TPB, 0, stream>>>(
            rs, col, posr, nvar, x, Wr, br,
            uW1, ub1, uW2, ub2, uW3, ub3,
            pW1, pb1, pW2, pb2, pW3, pb3,
            state, (float*)d_out, nvar2);
    }

    {   // clause partition (gather state via CSR, rows offset by 2nvar)
        int blocks = (ncla + BM - 1) / BM;
        fused_kernel<64><<<blocks, TPB, 0, stream>>>(
            rs + nvar2, col, state, nvar, x + (size_t)nvar2 * 3, Wc, bc,
            uW1, ub1, uW2, ub2, uW3, ub3,
            pW1, pb1, pW2, pb2, pW3, pb3,
            nullptr, (float*)d_out + (size_t)nvar2 * 2, ncla);
    }
}

// Round 9
// 1383.887 us; speedup vs baseline: 1.1686x; 1.1211x over previous
//
#include <hip/hip_runtime.h>

#define TPB 512
#define BM 64
#define AS 128   // activation row stride in floats (swizzled)

// ===========================================================================
// CSR build: count -> block scan -> fixup -> scatter. Rebuilt every call.
// ===========================================================================
__global__ void count_kernel(const int* __restrict__ ei, int* __restrict__ cnt, int E)
{
    int e = blockIdx.x * blockDim.x + threadIdx.x;
    if (e >= E) return;
    atomicAdd(cnt + ei[E + e], 1);
}

__global__ void scan_blocks(const int* __restrict__ cnt, int* __restrict__ rs,
                            int* __restrict__ part, int N)
{
    __shared__ int sums[256];
    int t = threadIdx.x;
    int base = blockIdx.x * 2048 + t * 8;
    int v[8], s = 0;
#pragma unroll
    for (int i = 0; i < 8; i++) { int idx = base + i; v[i] = (idx < N) ? cnt[idx] : 0; s += v[i]; }
    sums[t] = s;
    __syncthreads();
    for (int off = 1; off < 256; off <<= 1) {
        int x = (t >= off) ? sums[t - off] : 0;
        __syncthreads();
        if (t >= off) sums[t] += x;
        __syncthreads();
    }
    int run = (t == 0) ? 0 : sums[t - 1];
#pragma unroll
    for (int i = 0; i < 8; i++) { int idx = base + i; if (idx < N) rs[idx] = run; run += v[i]; }
    if (t == 255) part[blockIdx.x] = sums[255];
}

__global__ void scan_part(int* __restrict__ part, int nb)
{
    __shared__ int sums[256];
    int t = threadIdx.x;
    int base = t * 8;
    int v[8], s = 0;
#pragma unroll
    for (int i = 0; i < 8; i++) { int idx = base + i; v[i] = (idx < nb) ? part[idx] : 0; s += v[i]; }
    sums[t] = s;
    __syncthreads();
    for (int off = 1; off < 256; off <<= 1) {
        int x = (t >= off) ? sums[t - off] : 0;
        __syncthreads();
        if (t >= off) sums[t] += x;
        __syncthreads();
    }
    int run = (t == 0) ? 0 : sums[t - 1];
#pragma unroll
    for (int i = 0; i < 8; i++) { int idx = base + i; if (idx < nb) part[idx] = run; run += v[i]; }
}

__global__ void scan_fixup(int* __restrict__ rs, int* __restrict__ cursor,
                           const int* __restrict__ part, int N, int E)
{
    int i = blockIdx.x * blockDim.x + threadIdx.x;
    if (i < N) { int v = rs[i] + part[i >> 11]; rs[i] = v; cursor[i] = v; }
    if (i == 0) rs[N] = E;
}

__global__ void scatter_kernel(const int* __restrict__ ei, int* __restrict__ cursor,
                               int* __restrict__ col, int E)
{
    int e = blockIdx.x * blockDim.x + threadIdx.x;
    if (e >= E) return;
    int d = ei[E + e];
    int p = atomicAdd(cursor + d, 1);
    col[p] = ei[e];
}

// ===========================================================================
// act LDS swizzle: float4-slot XOR'd with (row&7); row-stride (lane=row)
// accesses spread across all banks (2 rows/bank-group = free).
// ===========================================================================
__device__ __forceinline__ int swz(int r, int col)
{
    return r * AS + ((((col >> 2) ^ (r & 7)) << 2) | (col & 3));
}

// ===========================================================================
// Scalar-weight GEMM layer: wave = 64 rows (lane=row) x CW=C/8 columns.
// W[k][c] wave-uniform -> s_load through K$; act read = 1 ds_read_b128 per
// 4 k per lane. BM=64 -> 32KB act LDS -> 4 blocks/CU (32 waves) so s_load
// latency and LDS waits interleave across 8 waves/SIMD.
//   act[r][0:C] = f(sum_k act[r][k]*W[k][c] + scale(r)*bias[c])  in place
// ===========================================================================
template<int C, bool RELU>
__device__ __forceinline__ void scalar_gemm(
    float* __restrict__ act,
    const float* __restrict__ Wg, const float* __restrict__ bias_g,
    const float* __restrict__ ldeg,            // non-null: scale = ldeg[r]
    int K_real, int K_pad,                     // K_pad multiple of 4
    float* __restrict__ state_g, long base, int n)
{
    constexpr int CW = C / 8;                  // columns per wave (16 or 8)
    const int tid  = threadIdx.x;
    const int wid  = __builtin_amdgcn_readfirstlane(tid >> 6);  // uniform
    const int lane = tid & 63;
    const int r    = lane;                     // lane = row
    const int c0   = wid * CW;                 // wave-uniform column base

    float acc[CW];
#pragma unroll
    for (int j = 0; j < CW; j++) acc[j] = 0.0f;

    for (int k4 = 0; k4 < K_pad; k4 += 4) {
        float4 a = *(const float4*)(act + r * AS + (((k4 >> 2) ^ (r & 7)) << 2));
#pragma unroll
        for (int kk = 0; kk < 4; kk++) {
            int gk = k4 + kk;
            int wrow = (gk < K_real) ? gk : 0;       // clamp (act pad col = 0)
            float av = (&a.x)[kk];
            const float* wr = Wg + (long)wrow * C + c0;   // uniform -> s_load
#pragma unroll
            for (int j4 = 0; j4 < CW / 4; j4++) {
                float4 wv = *(const float4*)(wr + j4 * 4);
                acc[j4 * 4 + 0] = fmaf(av, wv.x, acc[j4 * 4 + 0]);
                acc[j4 * 4 + 1] = fmaf(av, wv.y, acc[j4 * 4 + 1]);
                acc[j4 * 4 + 2] = fmaf(av, wv.z, acc[j4 * 4 + 2]);
                acc[j4 * 4 + 3] = fmaf(av, wv.w, acc[j4 * 4 + 3]);
            }
        }
    }
    float scale = (ldeg != nullptr) ? ldeg[r] : 1.0f;
    __syncthreads();       // all waves' act reads complete
#pragma unroll
    for (int j4 = 0; j4 < CW / 4; j4++) {
        int cc = c0 + j4 * 4;
        float4 bv = *(const float4*)(bias_g + cc);        // uniform -> s_load
        float4 o;
        o.x = acc[j4 * 4 + 0] + scale * bv.x;
        o.y = acc[j4 * 4 + 1] + scale * bv.y;
        o.z = acc[j4 * 4 + 2] + scale * bv.z;
        o.w = acc[j4 * 4 + 3] + scale * bv.w;
        if (RELU) {
            o.x = fmaxf(o.x, 0.0f); o.y = fmaxf(o.y, 0.0f);
            o.z = fmaxf(o.z, 0.0f); o.w = fmaxf(o.w, 0.0f);
        }
        *(float4*)(act + r * AS + (((cc >> 2) ^ (r & 7)) << 2)) = o;
        if (state_g != nullptr && base + r < n)
            *(float4*)(state_g + (base + r) * 64 + cc) = o;
    }
    __syncthreads();       // new act visible
}

// ===========================================================================
// Fused per-64-node-tile: CSR gather -> layer0 -> update MLP -> predictor.
// LDS = 32KB act + ldeg -> 4 blocks/CU; launch_bounds(512,8) caps VGPR at 64
// (round 8 measured exactly 64 with 2x the accumulators -> fits).
// ===========================================================================
template<int K0>
__global__ __launch_bounds__(TPB, 8)
void fused_kernel(const int* __restrict__ rs, const int* __restrict__ col,
                  const float* __restrict__ srcdat, int nvar,
                  const float* __restrict__ xg,
                  const float* __restrict__ W0, const float* __restrict__ b0,
                  const float* __restrict__ uW1, const float* __restrict__ ub1,
                  const float* __restrict__ uW2, const float* __restrict__ ub2,
                  const float* __restrict__ uW3, const float* __restrict__ ub3,
                  const float* __restrict__ pW1, const float* __restrict__ pb1,
                  const float* __restrict__ pW2, const float* __restrict__ pb2,
                  const float* __restrict__ pW3, const float* __restrict__ pb3,
                  float* __restrict__ state_g, float* __restrict__ outg, int n)
{
    __shared__ float act[BM * AS];
    __shared__ float ldeg[BM];

    const int tid = threadIdx.x;
    const long base = (long)blockIdx.x * BM;
    const int nvar2 = 2 * nvar;
    const int wave = tid >> 6;
    const int lane = tid & 63;

    // ---- CSR gather into act[:, 0:K0] (swizzled); deg -> ldeg
    if constexpr (K0 == 64) {
        for (int i = 0; i < 8; i++) {
            int node = wave * 8 + i;
            long g = base + node;
            int d0 = 0, d1 = 0;
            if (g < n) { d0 = rs[g]; d1 = rs[g + 1]; }
            float acc = 0.0f;
            int e = d0;
            for (; e + 4 <= d1; e += 4) {
                int s0 = col[e], s1 = col[e + 1], s2 = col[e + 2], s3 = col[e + 3];
                float a0 = (s0 < nvar2) ? srcdat[(long)s0 * 64 + lane] : 0.0f;
                float a1 = (s1 < nvar2) ? srcdat[(long)s1 * 64 + lane] : 0.0f;
                float a2 = (s2 < nvar2) ? srcdat[(long)s2 * 64 + lane] : 0.0f;
                float a3 = (s3 < nvar2) ? srcdat[(long)s3 * 64 + lane] : 0.0f;
                acc += a0 + a1 + a2 + a3;
            }
            for (; e < d1; e++) {
                int s = col[e];
                if (s < nvar2) acc += srcdat[(long)s * 64 + lane];
            }
            act[swz(node, lane)] = acc;
            if (lane == 0) ldeg[node] = (float)(d1 - d0);
        }
    } else {
        const int f = lane & 15, sub = lane >> 4;
        for (int i = 0; i < 2; i++) {
            int node = wave * 8 + i * 4 + sub;
            long g = base + node;
            int d0 = 0, d1 = 0;
            if (g < n) { d0 = rs[g]; d1 = rs[g + 1]; }
            float acc = 0.0f;
            int e = d0;
            for (; e + 2 <= d1; e += 2) {
                int s0 = col[e], s1 = col[e + 1];
                float a0 = 0.0f, a1 = 0.0f;
                if (s0 < nvar2) {
                    a0 = srcdat[(long)((s0 < nvar) ? s0 : s0 - nvar) * 16 + f];
                    if (s0 >= nvar) a0 = -a0;
                }
                if (s1 < nvar2) {
                    a1 = srcdat[(long)((s1 < nvar) ? s1 : s1 - nvar) * 16 + f];
                    if (s1 >= nvar) a1 = -a1;
                }
                acc += a0 + a1;
            }
            for (; e < d1; e++) {
                int s = col[e];
                if (s < nvar2) {
                    float a = srcdat[(long)((s < nvar) ? s : s - nvar) * 16 + f];
                    acc += (s < nvar) ? a : -a;
                }
            }
            act[swz(node, f)] = acc;
            if (f == 0) ldeg[node] = (float)(d1 - d0);
        }
    }
    // ---- stage x into cols 64..66, zero col 67 (disjoint from layer0's
    // read cols 0..K0-1 -> ordered by scalar_gemm's internal barrier)
    for (int idx = tid; idx < BM * 4; idx += TPB) {
        int node = idx >> 2, j = idx & 3;
        float v = 0.0f;
        if (j < 3 && base + node < n) v = xg[(base + node) * 3 + j];
        act[swz(node, 64 + j)] = v;
    }
    __syncthreads();

    // ---- layer0: msg = gather@W0 + deg*b0 (reads 0:K0, writes 0:64)
    scalar_gemm<64, false>(act, W0, b0, ldeg, K0, K0, nullptr, base, n);
    // ---- update MLP (uW1 is 67x128; K_pad=68 with wrow clamp, act[67]=0)
    scalar_gemm<128, true >(act, uW1, ub1, nullptr, 67, 68, nullptr, base, n);
    scalar_gemm<128, true >(act, uW2, ub2, nullptr, 128, 128, nullptr, base, n);
    scalar_gemm<64, false>(act, uW3, ub3, nullptr, 128, 128, state_g, base, n);
    // ---- predictor MLP
    scalar_gemm<128, true >(act, pW1, pb1, nullptr, 64, 64, nullptr, base, n);
    scalar_gemm<128, true >(act, pW2, pb2, nullptr, 128, 128, nullptr, base, n);

    // ---- predictor layer3: 128 -> 2 (tiny; pW3 hot in cache)
    if (tid < 128) {
        int r = tid >> 1, c = tid & 1;
        float acc = pb3[c];
        for (int k = 0; k < 128; k += 4) {
            float4 a = *(const float4*)(act + r * AS + (((k >> 2) ^ (r & 7)) << 2));
            acc = fmaf(a.x, pW3[(k + 0) * 2 + c], acc);
            acc = fmaf(a.y, pW3[(k + 1) * 2 + c], acc);
            acc = fmaf(a.z, pW3[(k + 2) * 2 + c], acc);
            acc = fmaf(a.w, pW3[(k + 3) * 2 + c], acc);
        }
        if (base + r < n) outg[(base + r) * 2 + c] = acc;
    }
}

// ===========================================================================
extern "C" void kernel_launch(void* const* d_in, const int* in_sizes, int n_in,
                              void* d_out, int out_size, void* d_ws, size_t ws_size,
                              hipStream_t stream)
{
    const float* x    = (const float*)d_in[0];
    const int*   ei   = (const int*)d_in[1];
    // d_in[2] = gate_type: fixed ordering [VAR*nvar, NEGVAR*nvar, CLAUSE*ncla]
    const float* posr = (const float*)d_in[3];
    const float* Wr   = (const float*)d_in[4];
    const float* br   = (const float*)d_in[5];
    const float* Wc   = (const float*)d_in[6];
    const float* bc   = (const float*)d_in[7];
    const float* uW1  = (const float*)d_in[8];
    const float* ub1  = (const float*)d_in[9];
    const float* uW2  = (const float*)d_in[10];
    const float* ub2  = (const float*)d_in[11];
    const float* uW3  = (const float*)d_in[12];
    const float* ub3  = (const float*)d_in[13];
    const float* pW1  = (const float*)d_in[14];
    const float* pb1  = (const float*)d_in[15];
    const float* pW2  = (const float*)d_in[16];
    const float* pb2  = (const float*)d_in[17];
    const float* pW3  = (const float*)d_in[18];
    const float* pb3  = (const float*)d_in[19];

    const int N     = in_sizes[0] / 3;
    const int E     = in_sizes[1] / 2;
    const int nvar  = in_sizes[3] / 16;
    const int nvar2 = 2 * nvar;
    const int ncla  = N - nvar2;

    // workspace carve-out
    int* cnt    = (int*)d_ws;              // [N]
    int* rs     = cnt + N;                 // [N+1]
    int* cursor = rs + N + 1;              // [N]
    int* part   = cursor + N;              // [2048]
    int* col    = part + 2048;             // [E]
    size_t foff = ((size_t)(col + E - (int*)d_ws) + 3) & ~(size_t)3;
    float* state = (float*)d_ws + foff;    // [2nvar*64]

    hipMemsetAsync(cnt, 0, (size_t)N * sizeof(int), stream);

    const int nb = (N + 2047) / 2048;
    count_kernel<<<(E + 255) / 256, 256, 0, stream>>>(ei, cnt, E);
    scan_blocks<<<nb, 256, 0, stream>>>(cnt, rs, part, N);
    scan_part<<<1, 256, 0, stream>>>(part, nb);
    scan_fixup<<<(N + 255) / 256, 256, 0, stream>>>(rs, cursor, part, N, E);
    scatter_kernel<<<(E + 255) / 256, 256, 0, stream>>>(ei, cursor, col, E);

    {   // var + negvar partitions (gather pos_random via CSR)
        int blocks = (nvar2 + BM - 1) / BM;
        fused_kernel<16><<<blocks, TPB, 0, stream>>>(
            rs, col, posr, nvar, x, Wr, br,
            uW1, ub1, uW2, ub2, uW3, ub3,
            pW1, pb1, pW2, pb2, pW3, pb3,
            state, (float*)d_out, nvar2);
    }

    {   // clause partition (gather state via CSR, rows offset by 2nvar)
        int blocks = (ncla + BM - 1) / BM;
        fused_kernel<64><<<blocks, TPB, 0, stream>>>(
            rs + nvar2, col, state, nvar, x + (size_t)nvar2 * 3, Wc, bc,
            uW1, ub1, uW2, ub2, uW3, ub3,
            pW1, pb1, pW2, pb2, pW3, pb3,
            nullptr, (float*)d_out + (size_t)nvar2 * 2, ncla);
    }
}